// Round 2
// baseline (888.551 us; speedup 1.0000x reference)
//
#include <hip/hip_runtime.h>
#include <hip/hip_bf16.h>

// Problem constants
#define T_TOK 1024
#define H_DIM 2048
#define I_DIM 768
#define E_NUM 32
#define K_TOP 4
#define NPAIR (T_TOK * K_TOP)          // 4096 routed (token, expert) pairs
#define TM 32                          // tokens per m-tile
#define MAX_SLOTS (NPAIR + E_NUM * TM) // 5120 (worst-case padding)

// ws layout (byte offsets)
#define WS_META   0                                   // int[512]
#define WS_TOKEN  2048                                // int[MAX_SLOTS]
#define WS_WEIGHT (WS_TOKEN + MAX_SLOTS * 4)          // float[MAX_SLOTS]
#define WS_HBUF   (WS_WEIGHT + MAX_SLOTS * 4)         // bf16[MAX_SLOTS][I_DIM]
#define WS_XB     (WS_HBUF + MAX_SLOTS * I_DIM * 2)   // bf16[T_TOK][H_DIM]

typedef __bf16 bf16x8 __attribute__((ext_vector_type(8)));
typedef float f32x4 __attribute__((ext_vector_type(4)));
typedef float f32x8 __attribute__((ext_vector_type(8)));

__device__ inline bf16x8 cvt8(f32x8 v) {
    bf16x8 r;
#pragma unroll
    for (int i = 0; i < 8; ++i) r[i] = (__bf16)v[i];
    return r;
}

// ---------------------------------------------------------------------------
// Routing: group (token,k) pairs by expert, pad each expert to multiple of TM.
// meta: [0]=total slots; [8+e]=slot base off[e]; [64+e]=ntiles[e]. Single block.
// ---------------------------------------------------------------------------
__global__ void moe_route(const int* __restrict__ ids,
                          const float* __restrict__ ew,
                          int* __restrict__ meta,
                          int* __restrict__ slot_tok,
                          float* __restrict__ slot_w) {
    __shared__ int cnt[E_NUM], off[E_NUM], cur[E_NUM];
    __shared__ int s_tot;
    const int tid = threadIdx.x;
    if (tid < E_NUM) cnt[tid] = 0;
    __syncthreads();
    for (int p = tid; p < NPAIR; p += blockDim.x)
        atomicAdd(&cnt[ids[p]], 1);
    __syncthreads();
    if (tid == 0) {
        int tot = 0;
        for (int e = 0; e < E_NUM; ++e) {
            int pad = (cnt[e] + TM - 1) / TM * TM;
            off[e] = tot;
            meta[8 + e]  = tot;        // slot base of expert e
            meta[64 + e] = pad / TM;   // m-tile count of expert e
            tot += pad;
        }
        meta[0] = tot;
        s_tot = tot;
    }
    __syncthreads();
    const int tot = s_tot;
    for (int s = tid; s < tot; s += blockDim.x) {
        slot_tok[s] = 0;     // padded slots point at token 0 with weight 0
        slot_w[s]   = 0.0f;
    }
    if (tid < E_NUM) cur[tid] = 0;
    __syncthreads();
    for (int p = tid; p < NPAIR; p += blockDim.x) {
        int e = ids[p];
        int i = atomicAdd(&cur[e], 1);
        int s = off[e] + i;
        slot_tok[s] = p / K_TOP;
        slot_w[s]   = ew[p];
    }
}

// ---------------------------------------------------------------------------
// One-time X fp32 -> bf16 cast.
// ---------------------------------------------------------------------------
__global__ __launch_bounds__(256) void moe_xcast(const float* __restrict__ X,
                                                 __hip_bfloat16* __restrict__ Xb) {
    const int i = (blockIdx.x * 256 + threadIdx.x) * 8;
    f32x8 v = *(const f32x8*)(X + i);
    *(bf16x8*)(void*)(Xb + i) = cvt8(v);
}

// ---------------------------------------------------------------------------
// Phase 1: h = silu(X Wg^T) * (X Wu^T), weight-read-once + register ping-pong.
// Block = (expert, 16-col chunk of I). 4 waves split m-tiles 4-way.
// Each k-step issues ALL of step k+1's loads before computing step k's MFMAs
// (static double-buffer -> ~8 loads in flight per wave, vs ~1 before).
// ---------------------------------------------------------------------------
template<int NMT>
__device__ __forceinline__ void gu_group(
    const __hip_bfloat16* __restrict__ Xb,
    const float* __restrict__ pg, const float* __restrict__ pu,
    const int* __restrict__ slot_tok,
    __hip_bfloat16* __restrict__ Hb,
    int off, int tile0, int n0, int col, int quad) {
    int s0[NMT];
    const __hip_bfloat16 *px0[NMT], *px1[NMT];
#pragma unroll
    for (int m = 0; m < NMT; ++m) {
        s0[m] = off + TM * (tile0 + 4 * m);
        px0[m] = Xb + (size_t)slot_tok[s0[m] + col] * H_DIM;
        px1[m] = Xb + (size_t)slot_tok[s0[m] + 16 + col] * H_DIM;
    }
    f32x4 ag0[NMT], ag1[NMT], au0[NMT], au1[NMT];
#pragma unroll
    for (int m = 0; m < NMT; ++m) {
        ag0[m] = {0.f,0.f,0.f,0.f}; ag1[m] = {0.f,0.f,0.f,0.f};
        au0[m] = {0.f,0.f,0.f,0.f}; au1[m] = {0.f,0.f,0.f,0.f};
    }
    const int kq = quad * 8;
    bf16x8 wg2[2], wu2[2];
    bf16x8 a02[2][NMT], a12[2][NMT];
    {   // prologue: fill buffer 0
        f32x8 g = *(const f32x8*)(pg + kq);
        f32x8 u = *(const f32x8*)(pu + kq);
#pragma unroll
        for (int m = 0; m < NMT; ++m) {
            a02[0][m] = *(const bf16x8*)(const void*)(px0[m] + kq);
            a12[0][m] = *(const bf16x8*)(const void*)(px1[m] + kq);
        }
        wg2[0] = cvt8(g); wu2[0] = cvt8(u);
    }

#define GU_STEP(CUR, IT) do {                                                  \
        const int kn_ = kq + ((IT) + 1) * 32;                                  \
        f32x8 g_ = *(const f32x8*)(pg + kn_);                                  \
        f32x8 u_ = *(const f32x8*)(pu + kn_);                                  \
        _Pragma("unroll")                                                      \
        for (int m = 0; m < NMT; ++m) {                                        \
            a02[1 - (CUR)][m] = *(const bf16x8*)(const void*)(px0[m] + kn_);   \
            a12[1 - (CUR)][m] = *(const bf16x8*)(const void*)(px1[m] + kn_);   \
        }                                                                      \
        _Pragma("unroll")                                                      \
        for (int m = 0; m < NMT; ++m) {                                        \
            ag0[m] = __builtin_amdgcn_mfma_f32_16x16x32_bf16(a02[(CUR)][m], wg2[(CUR)], ag0[m], 0, 0, 0); \
            ag1[m] = __builtin_amdgcn_mfma_f32_16x16x32_bf16(a12[(CUR)][m], wg2[(CUR)], ag1[m], 0, 0, 0); \
            au0[m] = __builtin_amdgcn_mfma_f32_16x16x32_bf16(a02[(CUR)][m], wu2[(CUR)], au0[m], 0, 0, 0); \
            au1[m] = __builtin_amdgcn_mfma_f32_16x16x32_bf16(a12[(CUR)][m], wu2[(CUR)], au1[m], 0, 0, 0); \
        }                                                                      \
        wg2[1 - (CUR)] = cvt8(g_); wu2[1 - (CUR)] = cvt8(u_);                  \
    } while (0)

    const int NIT = H_DIM / 32;  // 64 (even)
    for (int it = 0; it < NIT - 2; it += 2) {
        GU_STEP(0, it);
        GU_STEP(1, it + 1);
    }
    GU_STEP(0, NIT - 2);
#undef GU_STEP
    // final k-step: compute buffer 1, no prefetch
#pragma unroll
    for (int m = 0; m < NMT; ++m) {
        ag0[m] = __builtin_amdgcn_mfma_f32_16x16x32_bf16(a02[1][m], wg2[1], ag0[m], 0, 0, 0);
        ag1[m] = __builtin_amdgcn_mfma_f32_16x16x32_bf16(a12[1][m], wg2[1], ag1[m], 0, 0, 0);
        au0[m] = __builtin_amdgcn_mfma_f32_16x16x32_bf16(a02[1][m], wu2[1], au0[m], 0, 0, 0);
        au1[m] = __builtin_amdgcn_mfma_f32_16x16x32_bf16(a12[1][m], wu2[1], au1[m], 0, 0, 0);
    }

#pragma unroll
    for (int m = 0; m < NMT; ++m) {
#pragma unroll
        for (int r = 0; r < 4; ++r) {
            const int row = quad * 4 + r;
            float g0 = ag0[m][r], u0 = au0[m][r];
            float h0 = (g0 / (1.0f + __expf(-g0))) * u0;
            Hb[(size_t)(s0[m] + row) * I_DIM + n0 + col] = __float2bfloat16(h0);
            float g1 = ag1[m][r], u1 = au1[m][r];
            float h1 = (g1 / (1.0f + __expf(-g1))) * u1;
            Hb[(size_t)(s0[m] + 16 + row) * I_DIM + n0 + col] = __float2bfloat16(h1);
        }
    }
}

__global__ __launch_bounds__(256) void moe_gateup(
    const __hip_bfloat16* __restrict__ Xb,
    const float* __restrict__ Wg,
    const float* __restrict__ Wu,
    const int* __restrict__ meta,
    const int* __restrict__ slot_tok,
    __hip_bfloat16* __restrict__ Hb) {
    const int NCH = I_DIM / 16;  // 48
    const int e   = blockIdx.x / NCH;
    const int nch = blockIdx.x - e * NCH;
    const int lane = threadIdx.x & 63;
    const int wave = threadIdx.x >> 6;
    const int col  = lane & 15;
    const int quad = lane >> 4;
    const int n0 = nch * 16;

    const int off   = meta[8 + e];
    const int ntile = meta[64 + e];
    // wave w owns tiles w, w+4, w+8, ...
    const int nw = (ntile > wave) ? ((ntile - wave + 3) >> 2) : 0;
    if (nw == 0) return;  // wave-uniform; no __syncthreads in this kernel

    const size_t wrow = ((size_t)e * I_DIM + n0 + col) * H_DIM;
    const float* pg = Wg + wrow;
    const float* pu = Wu + wrow;

    for (int i0 = 0; i0 < nw; i0 += 2) {
        const int tile0 = wave + 4 * i0;
        if (nw - i0 >= 2) gu_group<2>(Xb, pg, pu, slot_tok, Hb, off, tile0, n0, col, quad);
        else              gu_group<1>(Xb, pg, pu, slot_tok, Hb, off, tile0, n0, col, quad);
    }
}

// ---------------------------------------------------------------------------
// Phase 2: y[t] += w * (h @ Wd^T), same ping-pong structure.
// Block = (expert, 16-col chunk of H); 4 waves split m-tiles 4-way.
// ---------------------------------------------------------------------------
template<int NMT>
__device__ __forceinline__ void dn_group(
    const float* __restrict__ pd,
    const int* __restrict__ slot_tok,
    const float* __restrict__ slot_w,
    const __hip_bfloat16* __restrict__ Hb,
    float* __restrict__ Y,
    int off, int tile0, int n0, int col, int quad) {
    int s0[NMT];
    const __hip_bfloat16 *ph0[NMT], *ph1[NMT];
#pragma unroll
    for (int m = 0; m < NMT; ++m) {
        s0[m] = off + TM * (tile0 + 4 * m);
        ph0[m] = Hb + (size_t)(s0[m] + col) * I_DIM;
        ph1[m] = Hb + (size_t)(s0[m] + 16 + col) * I_DIM;
    }
    f32x4 a0[NMT], a1[NMT];
#pragma unroll
    for (int m = 0; m < NMT; ++m) { a0[m] = {0.f,0.f,0.f,0.f}; a1[m] = {0.f,0.f,0.f,0.f}; }

    const int kq = quad * 8;
    bf16x8 w2[2];
    bf16x8 h02[2][NMT], h12[2][NMT];
    {   // prologue
        f32x8 w = *(const f32x8*)(pd + kq);
#pragma unroll
        for (int m = 0; m < NMT; ++m) {
            h02[0][m] = *(const bf16x8*)(const void*)(ph0[m] + kq);
            h12[0][m] = *(const bf16x8*)(const void*)(ph1[m] + kq);
        }
        w2[0] = cvt8(w);
    }

#define DN_STEP(CUR, IT) do {                                                  \
        const int kn_ = kq + ((IT) + 1) * 32;                                  \
        f32x8 w_ = *(const f32x8*)(pd + kn_);                                  \
        _Pragma("unroll")                                                      \
        for (int m = 0; m < NMT; ++m) {                                        \
            h02[1 - (CUR)][m] = *(const bf16x8*)(const void*)(ph0[m] + kn_);   \
            h12[1 - (CUR)][m] = *(const bf16x8*)(const void*)(ph1[m] + kn_);   \
        }                                                                      \
        _Pragma("unroll")                                                      \
        for (int m = 0; m < NMT; ++m) {                                        \
            a0[m] = __builtin_amdgcn_mfma_f32_16x16x32_bf16(h02[(CUR)][m], w2[(CUR)], a0[m], 0, 0, 0); \
            a1[m] = __builtin_amdgcn_mfma_f32_16x16x32_bf16(h12[(CUR)][m], w2[(CUR)], a1[m], 0, 0, 0); \
        }                                                                      \
        w2[1 - (CUR)] = cvt8(w_);                                              \
    } while (0)

    const int NIT = I_DIM / 32;  // 24 (even)
    for (int it = 0; it < NIT - 2; it += 2) {
        DN_STEP(0, it);
        DN_STEP(1, it + 1);
    }
    DN_STEP(0, NIT - 2);
#undef DN_STEP
#pragma unroll
    for (int m = 0; m < NMT; ++m) {
        a0[m] = __builtin_amdgcn_mfma_f32_16x16x32_bf16(h02[1][m], w2[1], a0[m], 0, 0, 0);
        a1[m] = __builtin_amdgcn_mfma_f32_16x16x32_bf16(h12[1][m], w2[1], a1[m], 0, 0, 0);
    }

#pragma unroll
    for (int m = 0; m < NMT; ++m) {
#pragma unroll
        for (int r = 0; r < 4; ++r) {
            const int row = quad * 4 + r;
            const int sA = s0[m] + row;
            atomicAdd(&Y[(size_t)slot_tok[sA] * H_DIM + n0 + col], a0[m][r] * slot_w[sA]);
            const int sB = s0[m] + 16 + row;
            atomicAdd(&Y[(size_t)slot_tok[sB] * H_DIM + n0 + col], a1[m][r] * slot_w[sB]);
        }
    }
}

__global__ __launch_bounds__(256) void moe_down(
    const float* __restrict__ Wd,
    const int* __restrict__ meta,
    const int* __restrict__ slot_tok,
    const float* __restrict__ slot_w,
    const __hip_bfloat16* __restrict__ Hb,
    float* __restrict__ Y) {
    const int NCH = H_DIM / 16;  // 128
    const int e   = blockIdx.x / NCH;
    const int nch = blockIdx.x - e * NCH;
    const int lane = threadIdx.x & 63;
    const int wave = threadIdx.x >> 6;
    const int col  = lane & 15;
    const int quad = lane >> 4;
    const int n0 = nch * 16;

    const int off   = meta[8 + e];
    const int ntile = meta[64 + e];
    const int nw = (ntile > wave) ? ((ntile - wave + 3) >> 2) : 0;
    if (nw == 0) return;

    const float* pd = Wd + ((size_t)e * H_DIM + n0 + col) * I_DIM;

    for (int i0 = 0; i0 < nw; i0 += 2) {
        const int tile0 = wave + 4 * i0;
        if (nw - i0 >= 2) dn_group<2>(pd, slot_tok, slot_w, Hb, Y, off, tile0, n0, col, quad);
        else              dn_group<1>(pd, slot_tok, slot_w, Hb, Y, off, tile0, n0, col, quad);
    }
}

extern "C" void kernel_launch(void* const* d_in, const int* in_sizes, int n_in,
                              void* d_out, int out_size, void* d_ws, size_t ws_size,
                              hipStream_t stream) {
    const float* X  = (const float*)d_in[0];
    const float* Wg = (const float*)d_in[1];
    const float* Wu = (const float*)d_in[2];
    const float* Wd = (const float*)d_in[3];
    const int* ids  = (const int*)d_in[4];
    const float* ew = (const float*)d_in[5];

    char* ws = (char*)d_ws;
    int*   meta     = (int*)(ws + WS_META);
    int*   slot_tok = (int*)(ws + WS_TOKEN);
    float* slot_w   = (float*)(ws + WS_WEIGHT);
    __hip_bfloat16* Hb = (__hip_bfloat16*)(ws + WS_HBUF);
    __hip_bfloat16* Xb = (__hip_bfloat16*)(ws + WS_XB);
    float* Y = (float*)d_out;  // fp32 output (reference returns float32)

    // d_out is re-poisoned before every timed launch — zero it ourselves.
    hipMemsetAsync(Y, 0, (size_t)T_TOK * H_DIM * sizeof(float), stream);
    moe_route<<<1, 256, 0, stream>>>(ids, ew, meta, slot_tok, slot_w);
    moe_xcast<<<(T_TOK * H_DIM / 8) / 256, 256, 0, stream>>>(X, Xb);
    moe_gateup<<<E_NUM * (I_DIM / 16), 256, 0, stream>>>(Xb, Wg, Wu, meta, slot_tok, Hb);
    moe_down<<<E_NUM * (H_DIM / 16), 256, 0, stream>>>(Wd, meta, slot_tok, slot_w, Hb, Y);
}

// Round 3
// 775.860 us; speedup vs baseline: 1.1452x; 1.1452x over previous
//
#include <hip/hip_runtime.h>
#include <hip/hip_bf16.h>

// Problem constants
#define T_TOK 1024
#define H_DIM 2048
#define I_DIM 768
#define E_NUM 32
#define K_TOP 4
#define NPAIR (T_TOK * K_TOP)          // 4096 routed (token, expert) pairs
#define TM 32                          // tokens per m-tile
#define MAX_SLOTS (NPAIR + E_NUM * TM) // 5120 (worst-case padding)

// ws layout (byte offsets)
#define WS_META   0                                   // int[512]
#define WS_TOKEN  2048                                // int[MAX_SLOTS]
#define WS_WEIGHT (WS_TOKEN + MAX_SLOTS * 4)          // float[MAX_SLOTS]
#define WS_HBUF   (WS_WEIGHT + MAX_SLOTS * 4)         // bf16[MAX_SLOTS][I_DIM]
#define WS_XB     (WS_HBUF + MAX_SLOTS * I_DIM * 2)   // bf16[T_TOK][H_DIM]

typedef __bf16 bf16x8 __attribute__((ext_vector_type(8)));
typedef float f32x4 __attribute__((ext_vector_type(4)));
typedef float f32x8 __attribute__((ext_vector_type(8)));

#define MFMA(acc, a, b) acc = __builtin_amdgcn_mfma_f32_16x16x32_bf16(a, b, acc, 0, 0, 0)

__device__ inline bf16x8 cvt8(f32x8 v) {
    bf16x8 r;
#pragma unroll
    for (int i = 0; i < 8; ++i) r[i] = (__bf16)v[i];
    return r;
}

// Async global->LDS, 16B per lane. LDS dest = wave-uniform base + lane*16.
__device__ __forceinline__ void stage16(const void* g, void* l) {
    __builtin_amdgcn_global_load_lds(
        (__attribute__((address_space(1))) void*)(void*)(size_t)g,
        (__attribute__((address_space(3))) void*)l, 16, 0, 0);
}

// Read one bf16x8 B-fragment from a [16 rows][64 f32] LDS weight tile.
// Row stride 256B; granule(16B) XOR-swizzled by (row&7) on both write & read.
__device__ __forceinline__ bf16x8 bfrag(const char* tile, int c, int jq) {
    const int key = (c & 7) << 4;
    f32x4 lo = *(const f32x4*)(tile + c * 256 + ((jq +  0) ^ key));
    f32x4 hi = *(const f32x4*)(tile + c * 256 + ((jq + 16) ^ key));
    f32x8 v;
    v[0] = lo[0]; v[1] = lo[1]; v[2] = lo[2]; v[3] = lo[3];
    v[4] = hi[0]; v[5] = hi[1]; v[6] = hi[2]; v[7] = hi[3];
    return cvt8(v);
}

// ---------------------------------------------------------------------------
// Routing: group (token,k) pairs by expert, pad each expert to multiple of TM.
// meta: [0]=total slots; [8+e]=slot base off[e]; [64+e]=ntiles[e]. Single block.
// ---------------------------------------------------------------------------
__global__ void moe_route(const int* __restrict__ ids,
                          const float* __restrict__ ew,
                          int* __restrict__ meta,
                          int* __restrict__ slot_tok,
                          float* __restrict__ slot_w) {
    __shared__ int cnt[E_NUM], off[E_NUM], cur[E_NUM];
    __shared__ int s_tot;
    const int tid = threadIdx.x;
    if (tid < E_NUM) cnt[tid] = 0;
    __syncthreads();
    for (int p = tid; p < NPAIR; p += blockDim.x)
        atomicAdd(&cnt[ids[p]], 1);
    __syncthreads();
    if (tid == 0) {
        int tot = 0;
        for (int e = 0; e < E_NUM; ++e) {
            int pad = (cnt[e] + TM - 1) / TM * TM;
            off[e] = tot;
            meta[8 + e]  = tot;        // slot base of expert e
            meta[64 + e] = pad / TM;   // m-tile count of expert e
            tot += pad;
        }
        meta[0] = tot;
        s_tot = tot;
    }
    __syncthreads();
    const int tot = s_tot;
    for (int s = tid; s < tot; s += blockDim.x) {
        slot_tok[s] = 0;     // padded slots point at token 0 with weight 0
        slot_w[s]   = 0.0f;
    }
    if (tid < E_NUM) cur[tid] = 0;
    __syncthreads();
    for (int p = tid; p < NPAIR; p += blockDim.x) {
        int e = ids[p];
        int i = atomicAdd(&cur[e], 1);
        int s = off[e] + i;
        slot_tok[s] = p / K_TOP;
        slot_w[s]   = ew[p];
    }
}

// ---------------------------------------------------------------------------
// One-time X fp32 -> bf16 cast.
// ---------------------------------------------------------------------------
__global__ __launch_bounds__(256) void moe_xcast(const float* __restrict__ X,
                                                 __hip_bfloat16* __restrict__ Xb) {
    const int i = (blockIdx.x * 256 + threadIdx.x) * 8;
    f32x8 v = *(const f32x8*)(X + i);
    *(bf16x8*)(void*)(Xb + i) = cvt8(v);
}

// ---------------------------------------------------------------------------
// Phase 1: h = silu(X Wg^T) * (X Wu^T).
// Block = (expert, 16-col chunk of I). Weight K-tile (16 rows x 64 f32, for
// both Wg and Wu) staged to LDS via global_load_lds, double-buffered:
//   stage(t+1) -> compute(t) -> __syncthreads().
// All 4 waves share the LDS B-tile; m-tiles split w::4, register-accumulated
// => every weight byte crosses HBM exactly once. A (Xb) = direct global loads
// (L2/L3-resident).
// ---------------------------------------------------------------------------
__global__ __launch_bounds__(256) void moe_gateup(
    const __hip_bfloat16* __restrict__ Xb,
    const float* __restrict__ Wg,
    const float* __restrict__ Wu,
    const int* __restrict__ meta,
    const int* __restrict__ slot_tok,
    __hip_bfloat16* __restrict__ Hb) {
    __shared__ __align__(16) char lds[2][2][4096];  // [buf][mat g/u][16r x 64 f32]
    const int NCH = I_DIM / 16;  // 48
    const int e   = blockIdx.x / NCH;
    const int nch = blockIdx.x - e * NCH;
    const int n0  = nch * 16;
    const int lane = threadIdx.x & 63;
    const int wave = threadIdx.x >> 6;
    const int c = lane & 15;
    const int q = lane >> 4;

    const int off   = meta[8 + e];
    const int ntile = meta[64 + e];
    if (ntile == 0) return;  // block-uniform

    // Staging: wave stages rows [wave*4, wave*4+4) of each 16-row tile.
    // lane -> row r_st, granule g; fetch global granule (g ^ (r&7)) so the
    // linear LDS write lands pre-swizzled (G21: source-perm == read-perm).
    const int r_st = wave * 4 + (lane >> 4);
    const int g_st = (lane & 15) ^ (r_st & 7);
    const size_t wbase = ((size_t)e * I_DIM + n0 + r_st) * H_DIM + (size_t)g_st * 4;
    const float* pgs = Wg + wbase;
    const float* pus = Wu + wbase;
    char* const ldg0 = &lds[0][0][0] + wave * 1024;
    char* const ldg1 = &lds[1][0][0] + wave * 1024;
    char* const ldu0 = &lds[0][1][0] + wave * 1024;
    char* const ldu1 = &lds[1][1][0] + wave * 1024;

    const int NT = H_DIM / 64;  // 32

    for (int p0 = 0; p0 < ntile; p0 += 8) {  // almost always one pass
        const int npass = ntile - p0 < 8 ? ntile - p0 : 8;
        const int nmt = (wave < npass ? 1 : 0) + (wave + 4 < npass ? 1 : 0);
        int s0a = off, s0b = off;
        int ta0 = 0, ta1 = 0, tb0 = 0, tb1 = 0;
        if (nmt >= 1) {
            s0a = off + TM * (p0 + wave);
            ta0 = slot_tok[s0a + c]; ta1 = slot_tok[s0a + 16 + c];
        }
        if (nmt >= 2) {
            s0b = off + TM * (p0 + wave + 4);
            tb0 = slot_tok[s0b + c]; tb1 = slot_tok[s0b + 16 + c];
        }
        const __hip_bfloat16* pa0 = Xb + (size_t)ta0 * H_DIM;
        const __hip_bfloat16* pa1 = Xb + (size_t)ta1 * H_DIM;
        const __hip_bfloat16* pb0 = Xb + (size_t)tb0 * H_DIM;
        const __hip_bfloat16* pb1 = Xb + (size_t)tb1 * H_DIM;

        f32x4 ag0a = {0,0,0,0}, ag0b = {0,0,0,0}, au0a = {0,0,0,0}, au0b = {0,0,0,0};
        f32x4 ag1a = {0,0,0,0}, ag1b = {0,0,0,0}, au1a = {0,0,0,0}, au1b = {0,0,0,0};

        // prologue: stage K-tile 0 into buf 0
        stage16(pgs, ldg0);
        stage16(pus, ldu0);
        __syncthreads();

        for (int t = 0; t < NT; ++t) {
            const int cur = t & 1;
            if (t + 1 < NT) {
                const float* pg_n = pgs + (t + 1) * 64;
                const float* pu_n = pus + (t + 1) * 64;
                stage16(pg_n, cur ? ldg0 : ldg1);
                stage16(pu_n, cur ? ldu0 : ldu1);
            }
            if (nmt > 0) {
                const char* tg = &lds[cur][0][0];
                const char* tu = &lds[cur][1][0];
                const int k0 = t * 64;
#pragma unroll
                for (int j = 0; j < 2; ++j) {
                    const int jq = j * 128 + q * 32;
                    bf16x8 bg = bfrag(tg, c, jq);
                    bf16x8 bu = bfrag(tu, c, jq);
                    const int ka = k0 + j * 32 + q * 8;
                    bf16x8 a0 = *(const bf16x8*)(const void*)(pa0 + ka);
                    bf16x8 a1 = *(const bf16x8*)(const void*)(pa1 + ka);
                    MFMA(ag0a, a0, bg); MFMA(au0a, a0, bu);
                    MFMA(ag0b, a1, bg); MFMA(au0b, a1, bu);
                    if (nmt > 1) {
                        bf16x8 b0 = *(const bf16x8*)(const void*)(pb0 + ka);
                        bf16x8 b1 = *(const bf16x8*)(const void*)(pb1 + ka);
                        MFMA(ag1a, b0, bg); MFMA(au1a, b0, bu);
                        MFMA(ag1b, b1, bg); MFMA(au1b, b1, bu);
                    }
                }
            }
            __syncthreads();
        }

        // epilogue: silu(gate)*up -> Hb
        if (nmt >= 1) {
#pragma unroll
            for (int r = 0; r < 4; ++r) {
                const int row = q * 4 + r;
                float g = ag0a[r], u = au0a[r];
                float h = (g / (1.0f + __expf(-g))) * u;
                Hb[(size_t)(s0a + row) * I_DIM + n0 + c] = __float2bfloat16(h);
                g = ag0b[r]; u = au0b[r];
                h = (g / (1.0f + __expf(-g))) * u;
                Hb[(size_t)(s0a + 16 + row) * I_DIM + n0 + c] = __float2bfloat16(h);
            }
        }
        if (nmt >= 2) {
#pragma unroll
            for (int r = 0; r < 4; ++r) {
                const int row = q * 4 + r;
                float g = ag1a[r], u = au1a[r];
                float h = (g / (1.0f + __expf(-g))) * u;
                Hb[(size_t)(s0b + row) * I_DIM + n0 + c] = __float2bfloat16(h);
                g = ag1b[r]; u = au1b[r];
                h = (g / (1.0f + __expf(-g))) * u;
                Hb[(size_t)(s0b + 16 + row) * I_DIM + n0 + c] = __float2bfloat16(h);
            }
        }
    }
}

// ---------------------------------------------------------------------------
// Phase 2: y[t] += w * (h @ Wd^T). Same staged structure; one weight matrix.
// ---------------------------------------------------------------------------
__global__ __launch_bounds__(256) void moe_down(
    const float* __restrict__ Wd,
    const int* __restrict__ meta,
    const int* __restrict__ slot_tok,
    const float* __restrict__ slot_w,
    const __hip_bfloat16* __restrict__ Hb,
    float* __restrict__ Y) {
    __shared__ __align__(16) char lds[2][4096];  // [buf][16 rows x 64 f32]
    const int NCH = H_DIM / 16;  // 128
    const int e   = blockIdx.x / NCH;
    const int nch = blockIdx.x - e * NCH;
    const int n0  = nch * 16;
    const int lane = threadIdx.x & 63;
    const int wave = threadIdx.x >> 6;
    const int c = lane & 15;
    const int q = lane >> 4;

    const int off   = meta[8 + e];
    const int ntile = meta[64 + e];
    if (ntile == 0) return;

    const int r_st = wave * 4 + (lane >> 4);
    const int g_st = (lane & 15) ^ (r_st & 7);
    const float* pds = Wd + ((size_t)e * H_DIM + n0 + r_st) * I_DIM + (size_t)g_st * 4;
    char* const ld0 = &lds[0][0] + wave * 1024;
    char* const ld1 = &lds[1][0] + wave * 1024;

    const int NT = I_DIM / 64;  // 12

    for (int p0 = 0; p0 < ntile; p0 += 8) {
        const int npass = ntile - p0 < 8 ? ntile - p0 : 8;
        const int nmt = (wave < npass ? 1 : 0) + (wave + 4 < npass ? 1 : 0);
        int s0a = off, s0b = off;
        if (nmt >= 1) s0a = off + TM * (p0 + wave);
        if (nmt >= 2) s0b = off + TM * (p0 + wave + 4);
        const __hip_bfloat16* pa0 = Hb + (size_t)(s0a + c) * I_DIM;
        const __hip_bfloat16* pa1 = Hb + (size_t)(s0a + 16 + c) * I_DIM;
        const __hip_bfloat16* pb0 = Hb + (size_t)(s0b + c) * I_DIM;
        const __hip_bfloat16* pb1 = Hb + (size_t)(s0b + 16 + c) * I_DIM;

        f32x4 a0a = {0,0,0,0}, a0b = {0,0,0,0}, a1a = {0,0,0,0}, a1b = {0,0,0,0};

        stage16(pds, ld0);
        __syncthreads();

        for (int t = 0; t < NT; ++t) {
            const int cur = t & 1;
            if (t + 1 < NT) stage16(pds + (t + 1) * 64, cur ? ld0 : ld1);
            if (nmt > 0) {
                const char* td = &lds[cur][0];
                const int k0 = t * 64;
#pragma unroll
                for (int j = 0; j < 2; ++j) {
                    const int jq = j * 128 + q * 32;
                    bf16x8 bd = bfrag(td, c, jq);
                    const int ka = k0 + j * 32 + q * 8;
                    bf16x8 h0 = *(const bf16x8*)(const void*)(pa0 + ka);
                    bf16x8 h1 = *(const bf16x8*)(const void*)(pa1 + ka);
                    MFMA(a0a, h0, bd); MFMA(a0b, h1, bd);
                    if (nmt > 1) {
                        bf16x8 h2 = *(const bf16x8*)(const void*)(pb0 + ka);
                        bf16x8 h3 = *(const bf16x8*)(const void*)(pb1 + ka);
                        MFMA(a1a, h2, bd); MFMA(a1b, h3, bd);
                    }
                }
            }
            __syncthreads();
        }

        if (nmt >= 1) {
#pragma unroll
            for (int r = 0; r < 4; ++r) {
                const int row = q * 4 + r;
                const int sA = s0a + row;
                atomicAdd(&Y[(size_t)slot_tok[sA] * H_DIM + n0 + c], a0a[r] * slot_w[sA]);
                const int sB = s0a + 16 + row;
                atomicAdd(&Y[(size_t)slot_tok[sB] * H_DIM + n0 + c], a0b[r] * slot_w[sB]);
            }
        }
        if (nmt >= 2) {
#pragma unroll
            for (int r = 0; r < 4; ++r) {
                const int row = q * 4 + r;
                const int sA = s0b + row;
                atomicAdd(&Y[(size_t)slot_tok[sA] * H_DIM + n0 + c], a1a[r] * slot_w[sA]);
                const int sB = s0b + 16 + row;
                atomicAdd(&Y[(size_t)slot_tok[sB] * H_DIM + n0 + c], a1b[r] * slot_w[sB]);
            }
        }
    }
}

extern "C" void kernel_launch(void* const* d_in, const int* in_sizes, int n_in,
                              void* d_out, int out_size, void* d_ws, size_t ws_size,
                              hipStream_t stream) {
    const float* X  = (const float*)d_in[0];
    const float* Wg = (const float*)d_in[1];
    const float* Wu = (const float*)d_in[2];
    const float* Wd = (const float*)d_in[3];
    const int* ids  = (const int*)d_in[4];
    const float* ew = (const float*)d_in[5];

    char* ws = (char*)d_ws;
    int*   meta     = (int*)(ws + WS_META);
    int*   slot_tok = (int*)(ws + WS_TOKEN);
    float* slot_w   = (float*)(ws + WS_WEIGHT);
    __hip_bfloat16* Hb = (__hip_bfloat16*)(ws + WS_HBUF);
    __hip_bfloat16* Xb = (__hip_bfloat16*)(ws + WS_XB);
    float* Y = (float*)d_out;  // fp32 output (reference returns float32)

    // d_out is re-poisoned before every timed launch — zero it ourselves.
    hipMemsetAsync(Y, 0, (size_t)T_TOK * H_DIM * sizeof(float), stream);
    moe_route<<<1, 256, 0, stream>>>(ids, ew, meta, slot_tok, slot_w);
    moe_xcast<<<(T_TOK * H_DIM / 8) / 256, 256, 0, stream>>>(X, Xb);
    moe_gateup<<<E_NUM * (I_DIM / 16), 256, 0, stream>>>(Xb, Wg, Wu, meta, slot_tok, Hb);
    moe_down<<<E_NUM * (H_DIM / 16), 256, 0, stream>>>(Wd, meta, slot_tok, slot_w, Hb, Y);
}